// Round 1
// baseline (1039.498 us; speedup 1.0000x reference)
//
#include <hip/hip_runtime.h>
#include <hip/hip_bf16.h>
#include <math.h>

// Problem constants
#define KF   7      // frames / groups
#define BB_  4      // batch
#define CC_  64     // channels per frame
#define HH   96
#define WW   96
#define HWSZ 9216   // 96*96
#define HEAD 256
#define CH2  448    // channels-last width of X2

typedef __bf16 bf16x8 __attribute__((ext_vector_type(8)));
typedef __bf16 bf16x4 __attribute__((ext_vector_type(4)));
typedef float  f32x4  __attribute__((ext_vector_type(4)));
typedef float  f32x2  __attribute__((ext_vector_type(2)));
typedef unsigned int u32;

// Packed fp32 helpers (VOP3P) + bf16 pack/unpack
__device__ __forceinline__ f32x2 pkmul(f32x2 a, f32x2 b) {
    f32x2 d; asm("v_pk_mul_f32 %0, %1, %2" : "=v"(d) : "v"(a), "v"(b)); return d;
}
__device__ __forceinline__ f32x2 pkfma(f32x2 a, f32x2 b, f32x2 c) {
    f32x2 d; asm("v_pk_fma_f32 %0, %1, %2, %3" : "=v"(d) : "v"(a), "v"(b), "v"(c)); return d;
}
__device__ __forceinline__ u32 cvtpk_bf16(f32x2 a) {
    u32 d; asm("v_cvt_pk_bf16_f32 %0, %1, %2" : "=v"(d) : "v"(a[0]), "v"(a[1])); return d;
}
__device__ __forceinline__ f32x2 unpk_bf16x2(u32 v) {
    f32x2 r;
    r[0] = __uint_as_float(v << 16);
    r[1] = __uint_as_float(v & 0xffff0000u);
    return r;
}

// ---------------------------------------------------------------------------
// features (K,B,C,H,W) fp32 -> X2[b][h][w][g*64+c] bf16 (channels-last)
// Block = one (g,b,h) row. LDS transpose for coalesced read AND write.
// ---------------------------------------------------------------------------
__global__ __launch_bounds__(256) void cvt_feat(const float* __restrict__ feat,
                                                __bf16* __restrict__ X2) {
    __shared__ float sT[96][65];
    const int h = blockIdx.x;
    const int n = blockIdx.y;          // g*4+b
    const int g = n >> 2, b = n & 3;
    const int t = threadIdx.x;
    const float* src = feat + (size_t)n * 64 * HWSZ + h * WW;
    for (int e = t; e < 6144; e += 256) {
        int c = e / 96, w = e - c * 96;
        sT[w][c] = src[(size_t)c * HWSZ + w];
    }
    __syncthreads();
    for (int u = t; u < 768; u += 256) {     // unit = 8 channels of one w
        int w = u >> 3, c8 = (u & 7) * 8;
        __bf16 tmp[8];
#pragma unroll
        for (int i = 0; i < 8; ++i) tmp[i] = (__bf16)sT[w][c8 + i];
        *(uint4*)&X2[(((size_t)(b * 96 + h)) * 96 + w) * CH2 + g * 64 + c8] =
            *(const uint4*)tmp;
    }
}

// ---------------------------------------------------------------------------
// Weight prep (unchanged)
// ---------------------------------------------------------------------------
__global__ __launch_bounds__(256) void cvt_taps(const float* __restrict__ w,
                                                __bf16* __restrict__ out,
                                                int Cout, int Cin, int CoutPad) {
    int e = blockIdx.x * 256 + threadIdx.x;
    int tot = Cout * Cin * 9;
    if (e >= tot) return;
    int co = e / (Cin * 9);
    int r  = e - co * (Cin * 9);
    int ci = r / 9;
    int k  = r - ci * 9;
    out[((size_t)k * CoutPad + co) * Cin + ci] = (__bf16)w[e];
}

__global__ __launch_bounds__(256) void cvt_flat(const float* __restrict__ w,
                                                __bf16* __restrict__ out, int n) {
    int e = blockIdx.x * 256 + threadIdx.x;
    if (e < n) out[e] = (__bf16)w[e];
}

// DCN weights: dcn_w[o][g*64+c][ktap] -> wA[o*4032 + g*576 + ktap*64 + c] bf16
__global__ __launch_bounds__(256) void cvt_dcnA(const float* __restrict__ w,
                                                __bf16* __restrict__ out) {
    int e = blockIdx.x * 256 + threadIdx.x;
    if (e >= 256 * 4032) return;
    int co = e / 4032;
    int r  = e - co * 4032;
    int g  = r / 576;
    int r2 = r - g * 576;
    int tap = r2 >> 6;
    int c   = r2 & 63;
    out[e] = (__bf16)w[((size_t)co * 448 + g * 64 + c) * 9 + tap];
}

// ---------------------------------------------------------------------------
// MFMA conv3x3 (+bias,+relu) -> optional MFMA 1x1 (+bias).
// Staging reads channels-last bf16 X2 with uint4 loads (no conversion).
// whMap: 1 -> b=img&3, chanBase=(img>>2)*64 (wh); 0 -> b=img, chanBase arg.
// ---------------------------------------------------------------------------
template<int MPW, int MODE>
__global__ __launch_bounds__(256) void conv3x3_mfma(
    const __bf16* __restrict__ X2,
    const __bf16* __restrict__ wT2,   // [(tap*CmidPad + co)*Cin + ci]
    const float* __restrict__ b1,
    const __bf16* __restrict__ w2b,   // [cf*256 + co]
    const float* __restrict__ b2,
    float* __restrict__ out,
    int Cin, int CmidPad, int Cf, int chanBase, int whMap)
{
    constexpr int SBYTES = (MODE == 2) ? 23520 : 50688;
    __shared__ __align__(16) char smem[SBYTES];
    __bf16 (*sX)[98][40] = (__bf16 (*)[98][40])smem;

    const int h    = blockIdx.x;
    const int img  = blockIdx.y;
    const int t    = threadIdx.x;
    const int wave = t >> 6;
    const int lane = t & 63;
    const int lq   = lane >> 4;
    const int lr   = lane & 15;
    const int mbase = wave * (MPW * 16);

    const int bImg = whMap ? (img & 3) : img;
    const int cb   = whMap ? ((img >> 2) * 64) : chanBase;
    const __bf16* Xrow = X2 + ((size_t)bImg * 96) * 96 * CH2;

    f32x4 acc[MPW][6];
#pragma unroll
    for (int mi = 0; mi < MPW; ++mi)
#pragma unroll
        for (int ni = 0; ni < 6; ++ni)
            acc[mi][ni] = (f32x4){0.f, 0.f, 0.f, 0.f};

    const int KC = Cin >> 5;
    for (int kc = 0; kc < KC; ++kc) {
        __syncthreads();
        // ---- stage: 294 positions x 32ch (64 B each) via uint4 ------------
        for (int u = t; u < 1176; u += 256) {
            int pos = u >> 2;
            int q   = u & 3;
            int r   = pos / 98;
            int gw  = pos - r * 98;
            int gh  = h - 1 + r;
            int gx  = gw - 1;
            uint4 v = {0u, 0u, 0u, 0u};
            if (((unsigned)gh < 96u) && ((unsigned)gx < 96u))
                v = *(const uint4*)&Xrow[((size_t)gh * 96 + gx) * CH2 +
                                         cb + kc * 32 + q * 8];
            *(uint4*)&sX[r][gw][q * 8] = v;
        }
        __syncthreads();

        const __bf16* wbase = wT2 + ((size_t)(mbase + lr)) * Cin + kc * 32 + lq * 8;
#pragma unroll
        for (int tap = 0; tap < 9; ++tap) {
            const int ky = tap / 3, kx = tap - ky * 3;
            bf16x8 aF[MPW];
#pragma unroll
            for (int mi = 0; mi < MPW; ++mi)
                aF[mi] = *(const bf16x8*)(wbase +
                          ((size_t)tap * CmidPad + mi * 16) * Cin);
#pragma unroll
            for (int ni = 0; ni < 6; ++ni) {
                bf16x8 bF = *(const bf16x8*)&sX[ky][ni * 16 + lr + kx][lq * 8];
#pragma unroll
                for (int mi = 0; mi < MPW; ++mi)
                    acc[mi][ni] = __builtin_amdgcn_mfma_f32_16x16x32_bf16(
                        aF[mi], bF, acc[mi][ni], 0, 0, 0);
            }
        }
    }

    if (MODE == 2) {
#pragma unroll
        for (int mi = 0; mi < MPW; ++mi)
#pragma unroll
            for (int ni = 0; ni < 6; ++ni) {
                int px = ni * 16 + lr;
#pragma unroll
                for (int r = 0; r < 4; ++r) {
                    int co = mbase + mi * 16 + lq * 4 + r;
                    if (co < Cf)
                        out[((size_t)(img * 189 + co)) * HWSZ + h * WW + px] =
                            acc[mi][ni][r] + b1[co];
                }
            }
        return;
    } else {
        __syncthreads();
        __bf16 (*sH)[264] = (__bf16 (*)[264])smem;
#pragma unroll
        for (int mi = 0; mi < MPW; ++mi) {
            int co0 = mbase + mi * 16 + lq * 4;
            float bb0 = b1[co0], bb1 = b1[co0 + 1], bb2 = b1[co0 + 2], bb3 = b1[co0 + 3];
#pragma unroll
            for (int ni = 0; ni < 6; ++ni) {
                int px = ni * 16 + lr;
                bf16x4 hv;
                hv[0] = (__bf16)fmaxf(acc[mi][ni][0] + bb0, 0.f);
                hv[1] = (__bf16)fmaxf(acc[mi][ni][1] + bb1, 0.f);
                hv[2] = (__bf16)fmaxf(acc[mi][ni][2] + bb2, 0.f);
                hv[3] = (__bf16)fmaxf(acc[mi][ni][3] + bb3, 0.f);
                *(bf16x4*)&sH[px][co0] = hv;
            }
        }
        __syncthreads();

        const int MT2 = (Cf + 15) >> 4;
        for (int tt = wave; tt < MT2 * 6; tt += 4) {
            int ni = tt / MT2;
            int mt = tt - ni * MT2;
            int cf = mt * 16 + lr; if (cf > Cf - 1) cf = Cf - 1;
            const __bf16* wrow = w2b + (size_t)cf * 256 + lq * 8;
            f32x4 c = (f32x4){0.f, 0.f, 0.f, 0.f};
#pragma unroll
            for (int kc = 0; kc < 8; ++kc) {
                bf16x8 aF = *(const bf16x8*)(wrow + kc * 32);
                bf16x8 bF = *(const bf16x8*)&sH[ni * 16 + lr][kc * 32 + lq * 8];
                c = __builtin_amdgcn_mfma_f32_16x16x32_bf16(aF, bF, c, 0, 0, 0);
            }
            int px = ni * 16 + lr;
#pragma unroll
            for (int r = 0; r < 4; ++r) {
                int cfr = mt * 16 + lq * 4 + r;
                if (cfr < Cf) {
                    int och;
                    if (MODE == 1) {
                        och = (img & 3) * 14 + (img >> 2) * 2 + cfr;
                    } else {
                        och = img * Cf + cfr;
                    }
                    out[(size_t)och * HWSZ + h * WW + px] = c[r] + b2[cfr];
                }
            }
        }
    }
}

// ---------------------------------------------------------------------------
// DCNv2 via MFMA + bias + BN + ReLU + bz 1x1, fused — SOFTWARE-PIPELINED.
// Per chunk (g,c3): P = compute addrs (from prefetched offmap), ISSUE corner
// loads into regs + prefetch next offmap; G = MFMA on previous chunk's LDS
// cols tile; W = wait corners, packed-f32 interp, write other LDS buffer.
// N-tile = 32 px so gather items (2 halves x 3 taps x 32 px = 192) fit one
// per thread (uniform pipeline VGPR cost). Grid 1152 blocks.
// ---------------------------------------------------------------------------
#define DNP 32
__global__ __launch_bounds__(256, 3) void dcn_bz_mfma(
    const __bf16* __restrict__ X2,
    const float* __restrict__ offmap,   // (B,189,H,W) fp32
    const __bf16* __restrict__ wA,      // [co][4032]
    const float* __restrict__ dcn_b,
    const float* __restrict__ bn_g, const float* __restrict__ bn_be,
    const float* __restrict__ bn_mn, const float* __restrict__ bn_vr,
    const __bf16* __restrict__ bzwb,    // [16][256]
    const float* __restrict__ bzb,
    float* __restrict__ out_bz)
{
    __shared__ __align__(16) char smem[30720];
    __bf16 (*sC)[6][DNP][40] = (__bf16 (*)[6][DNP][40])smem;  // [2] dbuf staging
    __bf16 (*sD)[DNP][40]    = (__bf16 (*)[DNP][40])smem;     // [8] epilogue

    const int b    = blockIdx.y;
    const int bxb  = blockIdx.x;
    const int h    = bxb / 3;
    const int w0   = (bxb - h * 3) * DNP;
    const int t    = threadIdx.x;
    const int wave = t >> 6;
    const int lane = t & 63;
    const int lq   = lane >> 4;
    const int lr   = lane & 15;
    const int mbase = wave * 64;

    const float* offp = offmap + (size_t)b * 189 * HWSZ;
    const __bf16* Xb  = X2 + ((size_t)b * 96) * 96 * CH2;

    // gather item: j = wave*48 + lane (lane<48). 192 items per chunk.
    const bool hasItem = (lane < 48);
    const int j    = wave * 48 + lane;
    const int tl   = j >> 6;            // tap-local 0..2  (== kx)
    const int half = (j >> 5) & 1;      // 32-ch half
    const int px   = j & 31;
    const int pix  = h * WW + w0 + px;

    f32x4 acc[4][2];
#pragma unroll
    for (int mi = 0; mi < 4; ++mi)
#pragma unroll
        for (int ni = 0; ni < 2; ++ni)
            acc[mi][ni] = (f32x4){0.f, 0.f, 0.f, 0.f};

    // ---- pipeline state (per item) ----------------------------------------
    float oy, ox, mv;                    // offmap values for the NEXT P chunk
    float w00, w01, w10, w11;            // bilinear*mask weights
    bf16x8 L00[4], L01[4], L10[4], L11[4];  // in-flight corner data (64 B/corner)

    // P: use (oy,ox,mv) for chunk cc -> weights + issue 16 corner loads;
    //    then prefetch offmap for chunk cc+1.
    auto Pphase = [&](int cc) {
        const int g  = cc / 3;
        const int c3 = cc - g * 3;       // == ky
        float m  = 1.f / (1.f + expf(-mv));
        float sy = (float)(h - 1 + c3) + oy;
        float sx = (float)(w0 + px - 1 + tl) + ox;
        float fy = floorf(sy), fx = floorf(sx);
        float wy = sy - fy,    wx = sx - fx;
        int y0 = (int)fy, x0 = (int)fx;
        int by = min(max(y0, 0), 94);
        int bx = min(max(x0, 0), 94);
        float wy0 = (y0 == by ? 1.f - wy : 0.f) + (y0 + 1 == by ? wy : 0.f);
        float wy1 = (y0 == by + 1 ? 1.f - wy : 0.f) + (y0 + 1 == by + 1 ? wy : 0.f);
        float wx0 = (x0 == bx ? 1.f - wx : 0.f) + (x0 + 1 == bx ? wx : 0.f);
        float wx1 = (x0 == bx + 1 ? 1.f - wx : 0.f) + (x0 + 1 == bx + 1 ? wx : 0.f);
        w00 = m * wy0 * wx0; w01 = m * wy0 * wx1;
        w10 = m * wy1 * wx0; w11 = m * wy1 * wx1;
        const __bf16* pl = Xb + ((size_t)by * 96 + bx) * CH2 + g * 64 + half * 32;
#pragma unroll
        for (int c8 = 0; c8 < 4; ++c8) {
            L00[c8] = *(const bf16x8*)(pl + c8 * 8);
            L01[c8] = *(const bf16x8*)(pl + CH2 + c8 * 8);
            L10[c8] = *(const bf16x8*)(pl + 96 * CH2 + c8 * 8);
            L11[c8] = *(const bf16x8*)(pl + 97 * CH2 + c8 * 8);
        }
        if (cc + 1 < 21) {               // prefetch offmap for next chunk
            int g2 = (cc + 1) / 3, c32 = (cc + 1) - g2 * 3;
            int gk = g2 * 9 + c32 * 3 + tl;
            oy = offp[(size_t)gk * HWSZ + pix];
            ox = offp[(size_t)(63 + gk) * HWSZ + pix];
            mv = offp[(size_t)(126 + gk) * HWSZ + pix];
        }
    };

    // W: wait corners (implicit via reg deps), packed-f32 interp, write LDS.
    auto Wphase = [&](int buf) {
        const int kc = tl * 2 + half;
        f32x2 vw00 = {w00, w00}, vw01 = {w01, w01};
        f32x2 vw10 = {w10, w10}, vw11 = {w11, w11};
#pragma unroll
        for (int c8 = 0; c8 < 4; ++c8) {
            const u32* p00 = (const u32*)&L00[c8];
            const u32* p01 = (const u32*)&L01[c8];
            const u32* p10 = (const u32*)&L10[c8];
            const u32* p11 = (const u32*)&L11[c8];
            u32 o[4];
#pragma unroll
            for (int p = 0; p < 4; ++p) {
                f32x2 a = pkmul(vw00, unpk_bf16x2(p00[p]));
                a = pkfma(vw01, unpk_bf16x2(p01[p]), a);
                a = pkfma(vw10, unpk_bf16x2(p10[p]), a);
                a = pkfma(vw11, unpk_bf16x2(p11[p]), a);
                o[p] = cvtpk_bf16(a);
            }
            *(uint4*)&sC[buf][kc][px][c8 * 8] = *(const uint4*)o;
        }
    };

    auto Gphase = [&](int cc, int buf) {
        const int g  = cc / 3;
        const int c3 = cc - g * 3;
        const __bf16* wbase = wA + (size_t)(mbase + lr) * 4032 +
                              (g * 18 + c3 * 6) * 32 + lq * 8;
#pragma unroll
        for (int kc = 0; kc < 6; ++kc) {
            bf16x8 aF[4];
#pragma unroll
            for (int mi = 0; mi < 4; ++mi)
                aF[mi] = *(const bf16x8*)(wbase + (size_t)mi * 16 * 4032 + kc * 32);
#pragma unroll
            for (int ni = 0; ni < 2; ++ni) {
                bf16x8 bF = *(const bf16x8*)&sC[buf][kc][ni * 16 + lr][lq * 8];
#pragma unroll
                for (int mi = 0; mi < 4; ++mi)
                    acc[mi][ni] = __builtin_amdgcn_mfma_f32_16x16x32_bf16(
                        aF[mi], bF, acc[mi][ni], 0, 0, 0);
            }
        }
    };

    // ---- prolog: offmap(0) -> P(0) -> W(0) into buf0 ----------------------
    if (hasItem) {
        oy = offp[(size_t)tl * HWSZ + pix];
        ox = offp[(size_t)(63 + tl) * HWSZ + pix];
        mv = offp[(size_t)(126 + tl) * HWSZ + pix];
        Pphase(0);
        Wphase(0);
    }

    // ---- main pipelined loop over 21 chunks -------------------------------
    for (int cc = 0; cc < 21; ++cc) {
        __syncthreads();                         // buf[cc&1] cols visible
        if (hasItem && cc + 1 < 21) Pphase(cc + 1);   // issue next corners
        __builtin_amdgcn_sched_barrier(0);       // pin load-issue before MFMA
        Gphase(cc, cc & 1);                      // corner latency hides here
        if (cc + 1 < 21) {
            __syncthreads();                     // all waves done with buf[(cc+1)&1]
            if (hasItem) Wphase((cc + 1) & 1);   // interp + write next buffer
        }
    }

    // ---- epilogue: bias + BN + relu -> channels-last bf16 LDS -------------
    __syncthreads();
#pragma unroll
    for (int mi = 0; mi < 4; ++mi) {
        int co0 = mbase + mi * 16 + lq * 4;
        float sc[4], sh[4];
#pragma unroll
        for (int r = 0; r < 4; ++r) {
            float s = bn_g[co0 + r] * rsqrtf(bn_vr[co0 + r] + 1e-5f);
            sc[r] = s;
            sh[r] = (dcn_b[co0 + r] - bn_mn[co0 + r]) * s + bn_be[co0 + r];
        }
#pragma unroll
        for (int ni = 0; ni < 2; ++ni) {
            int ppx = ni * 16 + lr;
            bf16x4 hv;
#pragma unroll
            for (int r = 0; r < 4; ++r)
                hv[r] = (__bf16)fmaxf(acc[mi][ni][r] * sc[r] + sh[r], 0.f);
            *(bf16x4*)&sD[co0 >> 5][ppx][co0 & 31] = hv;
        }
    }
    __syncthreads();

    // ---- bz 1x1: M=16, K=256, N=32 (2 n-tiles on waves 0..1) --------------
    if (wave < 2) {
        int ni = wave;
        const __bf16* wrow = bzwb + (size_t)lr * 256 + lq * 8;
        f32x4 c = (f32x4){0.f, 0.f, 0.f, 0.f};
#pragma unroll
        for (int kc = 0; kc < 8; ++kc) {
            bf16x8 aF = *(const bf16x8*)(wrow + kc * 32);
            bf16x8 bF = *(const bf16x8*)&sD[kc][ni * 16 + lr][lq * 8];
            c = __builtin_amdgcn_mfma_f32_16x16x32_bf16(aF, bF, c, 0, 0, 0);
        }
        int ppx = ni * 16 + lr;
#pragma unroll
        for (int r = 0; r < 4; ++r) {
            int cf = lq * 4 + r;
            out_bz[((size_t)(b * 16 + cf)) * HWSZ + h * WW + w0 + ppx] = c[r] + bzb[cf];
        }
    }
}

// ---------------------------------------------------------------------------
// Launch
// ---------------------------------------------------------------------------
extern "C" void kernel_launch(void* const* d_in, const int* in_sizes, int n_in,
                              void* d_out, int out_size, void* d_ws, size_t ws_size,
                              hipStream_t stream) {
    const float* feat   = (const float*)d_in[0];
    const float* hm_w1  = (const float*)d_in[1];
    const float* hm_b1  = (const float*)d_in[2];
    const float* hm_w2  = (const float*)d_in[3];
    const float* hm_b2  = (const float*)d_in[4];
    const float* wh_w1  = (const float*)d_in[5];
    const float* wh_b1  = (const float*)d_in[6];
    const float* wh_w2  = (const float*)d_in[7];
    const float* wh_b2  = (const float*)d_in[8];
    const float* id_w1  = (const float*)d_in[9];
    const float* id_b1  = (const float*)d_in[10];
    const float* id_w2  = (const float*)d_in[11];
    const float* id_b2  = (const float*)d_in[12];
    const float* off_w  = (const float*)d_in[13];
    const float* off_b  = (const float*)d_in[14];
    const float* dcn_w  = (const float*)d_in[15];
    const float* dcn_b  = (const float*)d_in[16];
    const float* bn_g   = (const float*)d_in[17];
    const float* bn_be  = (const float*)d_in[18];
    const float* bn_mn  = (const float*)d_in[19];
    const float* bn_vr  = (const float*)d_in[20];
    const float* bz_w   = (const float*)d_in[21];
    const float* bz_b   = (const float*)d_in[22];

    // Workspace layout
    float* ws      = (float*)d_ws;
    float* off_out = ws;                        // 6,967,296 f (27.9 MB)
    __bf16* X2     = (__bf16*)(off_out + 6967296); // 4*96*96*448 = 16,515,072 bf16
    __bf16* bfw    = X2 + 16515072;
    __bf16* wh_wT2 = bfw;                       // 147,456
    __bf16* hm_wT2 = wh_wT2 + 147456;           // 147,456
    __bf16* id_wT2 = hm_wT2 + 147456;           // 1,032,192
    __bf16* off_wT2= id_wT2 + 1032192;          // 774,144
    __bf16* wh_w2b = off_wT2 + 774144;          //     512
    __bf16* hm_w2b = wh_w2b + 512;              //    6144
    __bf16* id_w2b = hm_w2b + 6144;             //   32768
    __bf16* dcn_wA = id_w2b + 32768;            // 1,032,192
    __bf16* bz_wb  = dcn_wA + 1032192;          //    4096

    // Output layout (floats, concatenated): hm, bz, idout, owh
    float* out_hm = (float*)d_out;              // (4,24,96,96)
    float* out_bz = out_hm + 884736;            // (4,16,96,96)
    float* out_id = out_bz + 589824;            // (4,128,96,96)
    float* out_wh = out_id + 4718592;           // (4,14,96,96)

    // 1) data + weight prep
    cvt_feat<<<dim3(96, 28), 256, 0, stream>>>(feat, X2);
    cvt_taps<<<(147456 + 255) / 256, 256, 0, stream>>>(wh_w1, wh_wT2, 256, 64, 256);
    cvt_taps<<<(147456 + 255) / 256, 256, 0, stream>>>(hm_w1, hm_wT2, 256, 64, 256);
    cvt_taps<<<(1032192 + 255) / 256, 256, 0, stream>>>(id_w1, id_wT2, 256, 448, 256);
    cvt_taps<<<(762048 + 255) / 256, 256, 0, stream>>>(off_w, off_wT2, 189, 448, 192);
    cvt_flat<<<(512 + 255) / 256, 256, 0, stream>>>(wh_w2, wh_w2b, 512);
    cvt_flat<<<(6144 + 255) / 256, 256, 0, stream>>>(hm_w2, hm_w2b, 6144);
    cvt_flat<<<(32768 + 255) / 256, 256, 0, stream>>>(id_w2, id_w2b, 32768);
    cvt_flat<<<(4096 + 255) / 256, 256, 0, stream>>>(bz_w, bz_wb, 4096);
    cvt_dcnA<<<(1032192 + 255) / 256, 256, 0, stream>>>(dcn_w, dcn_wA);

    // 2) MFMA conv branches (staging from channels-last X2)
    conv3x3_mfma<4, 1><<<dim3(96, 28), 256, 0, stream>>>(
        X2, wh_wT2, wh_b1, wh_w2b, wh_b2, out_wh, 64, 256, 2, 0, 1);
    conv3x3_mfma<4, 0><<<dim3(96, 4), 256, 0, stream>>>(
        X2, hm_wT2, hm_b1, hm_w2b, hm_b2, out_hm, 64, 256, 24, 192, 0);
    conv3x3_mfma<4, 0><<<dim3(96, 4), 256, 0, stream>>>(
        X2, id_wT2, id_b1, id_w2b, id_b2, out_id, 448, 256, 128, 0, 0);
    conv3x3_mfma<3, 2><<<dim3(96, 4), 256, 0, stream>>>(
        X2, off_wT2, off_b, nullptr, nullptr, off_out, 448, 192, 189, 0, 0);

    // 3) DCN via MFMA + BN + ReLU + bz (pipelined, N-tile 32, grid 1152)
    dcn_bz_mfma<<<dim3(288, 4), 256, 0, stream>>>(
        X2, off_out, dcn_wA, dcn_b, bn_g, bn_be, bn_mn, bn_vr,
        bz_wb, bz_b, out_bz);
}

// Round 2
// 835.759 us; speedup vs baseline: 1.2438x; 1.2438x over previous
//
#include <hip/hip_runtime.h>
#include <hip/hip_bf16.h>
#include <math.h>

// Problem constants
#define KF   7      // frames / groups
#define BB_  4      // batch
#define CC_  64     // channels per frame
#define HH   96
#define WW   96
#define HWSZ 9216   // 96*96
#define HEAD 256
#define CH2  448    // channels-last width of X2

typedef __bf16 bf16x8 __attribute__((ext_vector_type(8)));
typedef __bf16 bf16x4 __attribute__((ext_vector_type(4)));
typedef float  f32x4  __attribute__((ext_vector_type(4)));
typedef float  f32x2  __attribute__((ext_vector_type(2)));
typedef unsigned int u32;

// Packed fp32 helpers (VOP3P) + bf16 pack/unpack
__device__ __forceinline__ f32x2 pkmul(f32x2 a, f32x2 b) {
    f32x2 d; asm("v_pk_mul_f32 %0, %1, %2" : "=v"(d) : "v"(a), "v"(b)); return d;
}
__device__ __forceinline__ f32x2 pkfma(f32x2 a, f32x2 b, f32x2 c) {
    f32x2 d; asm("v_pk_fma_f32 %0, %1, %2, %3" : "=v"(d) : "v"(a), "v"(b), "v"(c)); return d;
}
__device__ __forceinline__ u32 cvtpk_bf16(f32x2 a) {
    u32 d; asm("v_cvt_pk_bf16_f32 %0, %1, %2" : "=v"(d) : "v"(a[0]), "v"(a[1])); return d;
}
__device__ __forceinline__ f32x2 unpk_bf16x2(u32 v) {
    f32x2 r;
    r[0] = __uint_as_float(v << 16);
    r[1] = __uint_as_float(v & 0xffff0000u);
    return r;
}

// ---------------------------------------------------------------------------
// features (K,B,C,H,W) fp32 -> X2[b][h][w][g*64+c] bf16 (channels-last)
// ---------------------------------------------------------------------------
__global__ __launch_bounds__(256) void cvt_feat(const float* __restrict__ feat,
                                                __bf16* __restrict__ X2) {
    __shared__ float sT[96][65];
    const int h = blockIdx.x;
    const int n = blockIdx.y;          // g*4+b
    const int g = n >> 2, b = n & 3;
    const int t = threadIdx.x;
    const float* src = feat + (size_t)n * 64 * HWSZ + h * WW;
    for (int e = t; e < 6144; e += 256) {
        int c = e / 96, w = e - c * 96;
        sT[w][c] = src[(size_t)c * HWSZ + w];
    }
    __syncthreads();
    for (int u = t; u < 768; u += 256) {     // unit = 8 channels of one w
        int w = u >> 3, c8 = (u & 7) * 8;
        __bf16 tmp[8];
#pragma unroll
        for (int i = 0; i < 8; ++i) tmp[i] = (__bf16)sT[w][c8 + i];
        *(uint4*)&X2[(((size_t)(b * 96 + h)) * 96 + w) * CH2 + g * 64 + c8] =
            *(const uint4*)tmp;
    }
}

// ---------------------------------------------------------------------------
// Weight prep (unchanged)
// ---------------------------------------------------------------------------
__global__ __launch_bounds__(256) void cvt_taps(const float* __restrict__ w,
                                                __bf16* __restrict__ out,
                                                int Cout, int Cin, int CoutPad) {
    int e = blockIdx.x * 256 + threadIdx.x;
    int tot = Cout * Cin * 9;
    if (e >= tot) return;
    int co = e / (Cin * 9);
    int r  = e - co * (Cin * 9);
    int ci = r / 9;
    int k  = r - ci * 9;
    out[((size_t)k * CoutPad + co) * Cin + ci] = (__bf16)w[e];
}

__global__ __launch_bounds__(256) void cvt_flat(const float* __restrict__ w,
                                                __bf16* __restrict__ out, int n) {
    int e = blockIdx.x * 256 + threadIdx.x;
    if (e < n) out[e] = (__bf16)w[e];
}

// DCN weights: dcn_w[o][g*64+c][ktap] -> wA[o*4032 + g*576 + ktap*64 + c] bf16
__global__ __launch_bounds__(256) void cvt_dcnA(const float* __restrict__ w,
                                                __bf16* __restrict__ out) {
    int e = blockIdx.x * 256 + threadIdx.x;
    if (e >= 256 * 4032) return;
    int co = e / 4032;
    int r  = e - co * 4032;
    int g  = r / 576;
    int r2 = r - g * 576;
    int tap = r2 >> 6;
    int c   = r2 & 63;
    out[e] = (__bf16)w[((size_t)co * 448 + g * 64 + c) * 9 + tap];
}

// ---------------------------------------------------------------------------
// MFMA conv3x3 (+bias,+relu) -> optional MFMA 1x1 (+bias).
// ---------------------------------------------------------------------------
template<int MPW, int MODE>
__global__ __launch_bounds__(256) void conv3x3_mfma(
    const __bf16* __restrict__ X2,
    const __bf16* __restrict__ wT2,   // [(tap*CmidPad + co)*Cin + ci]
    const float* __restrict__ b1,
    const __bf16* __restrict__ w2b,   // [cf*256 + co]
    const float* __restrict__ b2,
    float* __restrict__ out,
    int Cin, int CmidPad, int Cf, int chanBase, int whMap)
{
    constexpr int SBYTES = (MODE == 2) ? 23520 : 50688;
    __shared__ __align__(16) char smem[SBYTES];
    __bf16 (*sX)[98][40] = (__bf16 (*)[98][40])smem;

    const int h    = blockIdx.x;
    const int img  = blockIdx.y;
    const int t    = threadIdx.x;
    const int wave = t >> 6;
    const int lane = t & 63;
    const int lq   = lane >> 4;
    const int lr   = lane & 15;
    const int mbase = wave * (MPW * 16);

    const int bImg = whMap ? (img & 3) : img;
    const int cb   = whMap ? ((img >> 2) * 64) : chanBase;
    const __bf16* Xrow = X2 + ((size_t)bImg * 96) * 96 * CH2;

    f32x4 acc[MPW][6];
#pragma unroll
    for (int mi = 0; mi < MPW; ++mi)
#pragma unroll
        for (int ni = 0; ni < 6; ++ni)
            acc[mi][ni] = (f32x4){0.f, 0.f, 0.f, 0.f};

    const int KC = Cin >> 5;
    for (int kc = 0; kc < KC; ++kc) {
        __syncthreads();
        // ---- stage: 294 positions x 32ch (64 B each) via uint4 ------------
        for (int u = t; u < 1176; u += 256) {
            int pos = u >> 2;
            int q   = u & 3;
            int r   = pos / 98;
            int gw  = pos - r * 98;
            int gh  = h - 1 + r;
            int gx  = gw - 1;
            uint4 v = {0u, 0u, 0u, 0u};
            if (((unsigned)gh < 96u) && ((unsigned)gx < 96u))
                v = *(const uint4*)&Xrow[((size_t)gh * 96 + gx) * CH2 +
                                         cb + kc * 32 + q * 8];
            *(uint4*)&sX[r][gw][q * 8] = v;
        }
        __syncthreads();

        const __bf16* wbase = wT2 + ((size_t)(mbase + lr)) * Cin + kc * 32 + lq * 8;
#pragma unroll
        for (int tap = 0; tap < 9; ++tap) {
            const int ky = tap / 3, kx = tap - ky * 3;
            bf16x8 aF[MPW];
#pragma unroll
            for (int mi = 0; mi < MPW; ++mi)
                aF[mi] = *(const bf16x8*)(wbase +
                          ((size_t)tap * CmidPad + mi * 16) * Cin);
#pragma unroll
            for (int ni = 0; ni < 6; ++ni) {
                bf16x8 bF = *(const bf16x8*)&sX[ky][ni * 16 + lr + kx][lq * 8];
#pragma unroll
                for (int mi = 0; mi < MPW; ++mi)
                    acc[mi][ni] = __builtin_amdgcn_mfma_f32_16x16x32_bf16(
                        aF[mi], bF, acc[mi][ni], 0, 0, 0);
            }
        }
    }

    if (MODE == 2) {
#pragma unroll
        for (int mi = 0; mi < MPW; ++mi)
#pragma unroll
            for (int ni = 0; ni < 6; ++ni) {
                int px = ni * 16 + lr;
#pragma unroll
                for (int r = 0; r < 4; ++r) {
                    int co = mbase + mi * 16 + lq * 4 + r;
                    if (co < Cf)
                        out[((size_t)(img * 189 + co)) * HWSZ + h * WW + px] =
                            acc[mi][ni][r] + b1[co];
                }
            }
        return;
    } else {
        __syncthreads();
        __bf16 (*sH)[264] = (__bf16 (*)[264])smem;
#pragma unroll
        for (int mi = 0; mi < MPW; ++mi) {
            int co0 = mbase + mi * 16 + lq * 4;
            float bb0 = b1[co0], bb1 = b1[co0 + 1], bb2 = b1[co0 + 2], bb3 = b1[co0 + 3];
#pragma unroll
            for (int ni = 0; ni < 6; ++ni) {
                int px = ni * 16 + lr;
                bf16x4 hv;
                hv[0] = (__bf16)fmaxf(acc[mi][ni][0] + bb0, 0.f);
                hv[1] = (__bf16)fmaxf(acc[mi][ni][1] + bb1, 0.f);
                hv[2] = (__bf16)fmaxf(acc[mi][ni][2] + bb2, 0.f);
                hv[3] = (__bf16)fmaxf(acc[mi][ni][3] + bb3, 0.f);
                *(bf16x4*)&sH[px][co0] = hv;
            }
        }
        __syncthreads();

        const int MT2 = (Cf + 15) >> 4;
        for (int tt = wave; tt < MT2 * 6; tt += 4) {
            int ni = tt / MT2;
            int mt = tt - ni * MT2;
            int cf = mt * 16 + lr; if (cf > Cf - 1) cf = Cf - 1;
            const __bf16* wrow = w2b + (size_t)cf * 256 + lq * 8;
            f32x4 c = (f32x4){0.f, 0.f, 0.f, 0.f};
#pragma unroll
            for (int kc = 0; kc < 8; ++kc) {
                bf16x8 aF = *(const bf16x8*)(wrow + kc * 32);
                bf16x8 bF = *(const bf16x8*)&sH[ni * 16 + lr][kc * 32 + lq * 8];
                c = __builtin_amdgcn_mfma_f32_16x16x32_bf16(aF, bF, c, 0, 0, 0);
            }
            int px = ni * 16 + lr;
#pragma unroll
            for (int r = 0; r < 4; ++r) {
                int cfr = mt * 16 + lq * 4 + r;
                if (cfr < Cf) {
                    int och;
                    if (MODE == 1) {
                        och = (img & 3) * 14 + (img >> 2) * 2 + cfr;
                    } else {
                        och = img * Cf + cfr;
                    }
                    out[(size_t)och * HWSZ + h * WW + px] = c[r] + b2[cfr];
                }
            }
        }
    }
}

// ---------------------------------------------------------------------------
// DCNv2 via MFMA + bias + BN + ReLU + bz 1x1, fused.
// v2 gather: per chunk (g,c3):
//   A) threads 0..143 compute bilinear weights + clamped base index once per
//      (tap,px) pair (offmap reads COALESCED) -> small LDS table.
//   B) 8-lane groups gather: each lane loads 8 consecutive channels; corner
//      base is 128B-aligned -> ONE cache-line request per corner per pair
//      (8x fewer VMEM requests than per-thread 16B scatter).  Packed-f32
//      interp -> bf16 cols tile in LDS.
//   C) MFMA GEMM over the K=192 chunk (unchanged).
// Block mapping XCD-swizzled: each XCD covers 48 contiguous h rows of one
// batch (~4MB X2 footprint ~= one L2).
// ---------------------------------------------------------------------------
#define DNP 48
__global__ __launch_bounds__(256) void dcn_bz_mfma(
    const __bf16* __restrict__ X2,
    const float* __restrict__ offmap,   // (B,189,H,W) fp32
    const __bf16* __restrict__ wA,      // [co][4032]
    const float* __restrict__ dcn_b,
    const float* __restrict__ bn_g, const float* __restrict__ bn_be,
    const float* __restrict__ bn_mn, const float* __restrict__ bn_vr,
    const __bf16* __restrict__ bzwb,    // [16][256]
    const float* __restrict__ bzb,
    float* __restrict__ out_bz)
{
    __shared__ __align__(16) char smem[33600];
    __bf16 (*sC)[DNP][40] = (__bf16 (*)[DNP][40])smem;   // [6][48][40] staging
    __bf16 (*sD)[DNP][40] = (__bf16 (*)[DNP][40])smem;   // [8][48][40] epilogue
    float4* sW4   = (float4*)(smem + 30720);              // [144] corner weights
    int*    sWoff = (int*)  (smem + 30720 + 2304);        // [144] clamped base

    // XCD-aware bijective swizzle: dispatch order is x-fastest; fid%8 = XCD.
    const int fid = blockIdx.x + blockIdx.y * 192;
    const int nf  = (fid & 7) * 96 + (fid >> 3);
    const int b   = nf / 192;
    const int r_  = nf - b * 192;
    const int h   = r_ >> 1;
    const int w0  = (r_ & 1) * DNP;

    const int t    = threadIdx.x;
    const int wave = t >> 6;
    const int lane = t & 63;
    const int lq   = lane >> 4;
    const int lr   = lane & 15;
    const int mbase = wave * 64;
    const int grp  = t >> 3;           // 8-lane gather group 0..31
    const int lsub = t & 7;

    const float* offp = offmap + (size_t)b * 189 * HWSZ;
    const __bf16* Xb  = X2 + ((size_t)b * 96) * 96 * CH2;

    f32x4 acc[4][3];
#pragma unroll
    for (int mi = 0; mi < 4; ++mi)
#pragma unroll
        for (int ni = 0; ni < 3; ++ni)
            acc[mi][ni] = (f32x4){0.f, 0.f, 0.f, 0.f};

    for (int g = 0; g < KF; ++g) {
        for (int c3 = 0; c3 < 3; ++c3) {
            __syncthreads();   // prev GEMM done with sC; sW reusable
            // ---- A: weights + base per (tap,px) pair, coalesced offmap ----
            if (t < 144) {
                int tl = t / 48;             // kx
                int px = t - tl * 48;
                int pix = h * WW + w0 + px;
                int gk  = g * 9 + c3 * 3 + tl;
                float oy = offp[(size_t)gk * HWSZ + pix];
                float ox = offp[(size_t)(63 + gk) * HWSZ + pix];
                float mv = offp[(size_t)(126 + gk) * HWSZ + pix];
                float m  = 1.f / (1.f + expf(-mv));
                float sy = (float)(h - 1 + c3) + oy;
                float sx = (float)(w0 + px - 1 + tl) + ox;
                float fy = floorf(sy), fx = floorf(sx);
                float wy = sy - fy,    wx = sx - fx;
                int y0 = (int)fy, x0 = (int)fx;
                int by = min(max(y0, 0), 94);
                int bx = min(max(x0, 0), 94);
                float wy0 = (y0 == by ? 1.f - wy : 0.f) + (y0 + 1 == by ? wy : 0.f);
                float wy1 = (y0 == by + 1 ? 1.f - wy : 0.f) + (y0 + 1 == by + 1 ? wy : 0.f);
                float wx0 = (x0 == bx ? 1.f - wx : 0.f) + (x0 + 1 == bx ? wx : 0.f);
                float wx1 = (x0 == bx + 1 ? 1.f - wx : 0.f) + (x0 + 1 == bx + 1 ? wx : 0.f);
                float4 wv;
                wv.x = m * wy0 * wx0; wv.y = m * wy0 * wx1;
                wv.z = m * wy1 * wx0; wv.w = m * wy1 * wx1;
                sW4[t]   = wv;
                sWoff[t] = by * 96 + bx;
            }
            __syncthreads();   // sW ready
            // ---- B: cooperative gather, 8 lanes = 64 ch of one pair -------
            for (int p = grp; p < 144; p += 32) {
                float4 wv = sW4[p];
                int base  = sWoff[p];
                int tl = p / 48;
                int px = p - tl * 48;
                const __bf16* pl = Xb + (size_t)base * CH2 + g * 64 + lsub * 8;
                bf16x8 c00 = *(const bf16x8*)(pl);
                bf16x8 c01 = *(const bf16x8*)(pl + CH2);
                bf16x8 c10 = *(const bf16x8*)(pl + 96 * CH2);
                bf16x8 c11 = *(const bf16x8*)(pl + 97 * CH2);
                f32x2 vw00 = {wv.x, wv.x}, vw01 = {wv.y, wv.y};
                f32x2 vw10 = {wv.z, wv.z}, vw11 = {wv.w, wv.w};
                const u32* p00 = (const u32*)&c00;
                const u32* p01 = (const u32*)&c01;
                const u32* p10 = (const u32*)&c10;
                const u32* p11 = (const u32*)&c11;
                u32 o[4];
#pragma unroll
                for (int pp = 0; pp < 4; ++pp) {
                    f32x2 a = pkmul(vw00, unpk_bf16x2(p00[pp]));
                    a = pkfma(vw01, unpk_bf16x2(p01[pp]), a);
                    a = pkfma(vw10, unpk_bf16x2(p10[pp]), a);
                    a = pkfma(vw11, unpk_bf16x2(p11[pp]), a);
                    o[pp] = cvtpk_bf16(a);
                }
                int kc = tl * 2 + (lsub >> 2);
                *(uint4*)&sC[kc][px][(lsub & 3) * 8] = *(const uint4*)o;
            }
            __syncthreads();   // cols ready
            // ---- C: GEMM over this K=192 chunk (6 sub-chunks of 32) -------
            const __bf16* wbase = wA + (size_t)(mbase + lr) * 4032 +
                                  (g * 18 + c3 * 6) * 32 + lq * 8;
#pragma unroll
            for (int kc = 0; kc < 6; ++kc) {
                bf16x8 aF[4];
#pragma unroll
                for (int mi = 0; mi < 4; ++mi)
                    aF[mi] = *(const bf16x8*)(wbase + (size_t)mi * 16 * 4032 + kc * 32);
#pragma unroll
                for (int ni = 0; ni < 3; ++ni) {
                    bf16x8 bF = *(const bf16x8*)&sC[kc][ni * 16 + lr][lq * 8];
#pragma unroll
                    for (int mi = 0; mi < 4; ++mi)
                        acc[mi][ni] = __builtin_amdgcn_mfma_f32_16x16x32_bf16(
                            aF[mi], bF, acc[mi][ni], 0, 0, 0);
                }
            }
        }
    }

    // ---- epilogue: bias + BN + relu -> channels-last bf16 LDS -------------
    __syncthreads();
#pragma unroll
    for (int mi = 0; mi < 4; ++mi) {
        int co0 = mbase + mi * 16 + lq * 4;
        float sc[4], sh[4];
#pragma unroll
        for (int r = 0; r < 4; ++r) {
            float s = bn_g[co0 + r] * rsqrtf(bn_vr[co0 + r] + 1e-5f);
            sc[r] = s;
            sh[r] = (dcn_b[co0 + r] - bn_mn[co0 + r]) * s + bn_be[co0 + r];
        }
#pragma unroll
        for (int ni = 0; ni < 3; ++ni) {
            int px = ni * 16 + lr;
            bf16x4 hv;
#pragma unroll
            for (int r = 0; r < 4; ++r)
                hv[r] = (__bf16)fmaxf(acc[mi][ni][r] * sc[r] + sh[r], 0.f);
            *(bf16x4*)&sD[co0 >> 5][px][co0 & 31] = hv;
        }
    }
    __syncthreads();

    // ---- bz 1x1: M=16, K=256, N=48 (3 n-tiles on waves 0..2) --------------
    if (wave < 3) {
        int ni = wave;
        const __bf16* wrow = bzwb + (size_t)lr * 256 + lq * 8;
        f32x4 c = (f32x4){0.f, 0.f, 0.f, 0.f};
#pragma unroll
        for (int kc = 0; kc < 8; ++kc) {
            bf16x8 aF = *(const bf16x8*)(wrow + kc * 32);
            bf16x8 bF = *(const bf16x8*)&sD[kc][ni * 16 + lr][lq * 8];
            c = __builtin_amdgcn_mfma_f32_16x16x32_bf16(aF, bF, c, 0, 0, 0);
        }
        int px = ni * 16 + lr;
#pragma unroll
        for (int r = 0; r < 4; ++r) {
            int cf = lq * 4 + r;
            out_bz[((size_t)(b * 16 + cf)) * HWSZ + h * WW + w0 + px] = c[r] + bzb[cf];
        }
    }
}

// ---------------------------------------------------------------------------
// Launch
// ---------------------------------------------------------------------------
extern "C" void kernel_launch(void* const* d_in, const int* in_sizes, int n_in,
                              void* d_out, int out_size, void* d_ws, size_t ws_size,
                              hipStream_t stream) {
    const float* feat   = (const float*)d_in[0];
    const float* hm_w1  = (const float*)d_in[1];
    const float* hm_b1  = (const float*)d_in[2];
    const float* hm_w2  = (const float*)d_in[3];
    const float* hm_b2  = (const float*)d_in[4];
    const float* wh_w1  = (const float*)d_in[5];
    const float* wh_b1  = (const float*)d_in[6];
    const float* wh_w2  = (const float*)d_in[7];
    const float* wh_b2  = (const float*)d_in[8];
    const float* id_w1  = (const float*)d_in[9];
    const float* id_b1  = (const float*)d_in[10];
    const float* id_w2  = (const float*)d_in[11];
    const float* id_b2  = (const float*)d_in[12];
    const float* off_w  = (const float*)d_in[13];
    const float* off_b  = (const float*)d_in[14];
    const float* dcn_w  = (const float*)d_in[15];
    const float* dcn_b  = (const float*)d_in[16];
    const float* bn_g   = (const float*)d_in[17];
    const float* bn_be  = (const float*)d_in[18];
    const float* bn_mn  = (const float*)d_in[19];
    const float* bn_vr  = (const float*)d_in[20];
    const float* bz_w   = (const float*)d_in[21];
    const float* bz_b   = (const float*)d_in[22];

    // Workspace layout
    float* ws      = (float*)d_ws;
    float* off_out = ws;                        // 6,967,296 f (27.9 MB)
    __bf16* X2     = (__bf16*)(off_out + 6967296); // 4*96*96*448 = 16,515,072 bf16
    __bf16* bfw    = X2 + 16515072;
    __bf16* wh_wT2 = bfw;                       // 147,456
    __bf16* hm_wT2 = wh_wT2 + 147456;           // 147,456
    __bf16* id_wT2 = hm_wT2 + 147456;           // 1,032,192
    __bf16* off_wT2= id_wT2 + 1032192;          // 774,144
    __bf16* wh_w2b = off_wT2 + 774144;          //     512
    __bf16* hm_w2b = wh_w2b + 512;              //    6144
    __bf16* id_w2b = hm_w2b + 6144;             //   32768
    __bf16* dcn_wA = id_w2b + 32768;            // 1,032,192
    __bf16* bz_wb  = dcn_wA + 1032192;          //    4096

    // Output layout (floats, concatenated): hm, bz, idout, owh
    float* out_hm = (float*)d_out;              // (4,24,96,96)
    float* out_bz = out_hm + 884736;            // (4,16,96,96)
    float* out_id = out_bz + 589824;            // (4,128,96,96)
    float* out_wh = out_id + 4718592;           // (4,14,96,96)

    // 1) data + weight prep
    cvt_feat<<<dim3(96, 28), 256, 0, stream>>>(feat, X2);
    cvt_taps<<<(147456 + 255) / 256, 256, 0, stream>>>(wh_w1, wh_wT2, 256, 64, 256);
    cvt_taps<<<(147456 + 255) / 256, 256, 0, stream>>>(hm_w1, hm_wT2, 256, 64, 256);
    cvt_taps<<<(1032192 + 255) / 256, 256, 0, stream>>>(id_w1, id_wT2, 256, 448, 256);
    cvt_taps<<<(762048 + 255) / 256, 256, 0, stream>>>(off_w, off_wT2, 189, 448, 192);
    cvt_flat<<<(512 + 255) / 256, 256, 0, stream>>>(wh_w2, wh_w2b, 512);
    cvt_flat<<<(6144 + 255) / 256, 256, 0, stream>>>(hm_w2, hm_w2b, 6144);
    cvt_flat<<<(32768 + 255) / 256, 256, 0, stream>>>(id_w2, id_w2b, 32768);
    cvt_flat<<<(4096 + 255) / 256, 256, 0, stream>>>(bz_w, bz_wb, 4096);
    cvt_dcnA<<<(1032192 + 255) / 256, 256, 0, stream>>>(dcn_w, dcn_wA);

    // 2) MFMA conv branches (staging from channels-last X2)
    conv3x3_mfma<4, 1><<<dim3(96, 28), 256, 0, stream>>>(
        X2, wh_wT2, wh_b1, wh_w2b, wh_b2, out_wh, 64, 256, 2, 0, 1);
    conv3x3_mfma<4, 0><<<dim3(96, 4), 256, 0, stream>>>(
        X2, hm_wT2, hm_b1, hm_w2b, hm_b2, out_hm, 64, 256, 24, 192, 0);
    conv3x3_mfma<4, 0><<<dim3(96, 4), 256, 0, stream>>>(
        X2, id_wT2, id_b1, id_w2b, id_b2, out_id, 448, 256, 128, 0, 0);
    conv3x3_mfma<3, 2><<<dim3(96, 4), 256, 0, stream>>>(
        X2, off_wT2, off_b, nullptr, nullptr, off_out, 448, 192, 189, 0, 0);

    // 3) DCN via MFMA + BN + ReLU + bz (cooperative gather, XCD swizzle)
    dcn_bz_mfma<<<dim3(192, 4), 256, 0, stream>>>(
        X2, off_out, dcn_wA, dcn_b, bn_g, bn_be, bn_mn, bn_vr,
        bz_wb, bz_b, out_bz);
}